// Round 1
// baseline (714.483 us; speedup 1.0000x reference)
//
#include <hip/hip_runtime.h>
#include <stdint.h>

// Problem constants
#define BATCH  8
#define CH     256
#define HH     96
#define WW     96
#define NHEADS 8
#define HD     32
#define KS     7
#define HWP    (HH*WW)          // 9216 pixels per image
#define SCALE  0.17677669529663687f   // 1/sqrt(32)

typedef unsigned short ushort_t;
typedef unsigned short us8 __attribute__((ext_vector_type(8)));
typedef short s8v __attribute__((ext_vector_type(8)));   // 8 bf16 in shorts (4 VGPRs) — MFMA A/B frag
typedef float f4v __attribute__((ext_vector_type(4)));   // MFMA C/D frag

// fp32 -> bf16 RNE
__device__ __forceinline__ ushort_t f2bf(float f){
  unsigned int u = __float_as_uint(f);
  u = u + 0x7fffu + ((u >> 16) & 1u);
  return (ushort_t)(u >> 16);
}
// unpack low/high bf16 of a uint to fp32
__device__ __forceinline__ float bflo(unsigned int u){ return __uint_as_float(u << 16); }
__device__ __forceinline__ float bfhi(unsigned int u){ return __uint_as_float(u & 0xffff0000u); }

// async global->LDS, 16B per lane; LDS dest = wave-uniform base + lane*16
__device__ __forceinline__ void gload_lds16(const void* g, void* l){
  __builtin_amdgcn_global_load_lds(
      (const __attribute__((address_space(1))) void*)g,
      (__attribute__((address_space(3))) void*)l, 16, 0, 0);
}

// ---------------------------------------------------------------- kernel 1
// convert wq|wk|wv|w_proj (each 256x256 fp32, [o][c]) to bf16, concatenated
__global__ __launch_bounds__(256) void wcvt_kernel(
    const float* __restrict__ wq, const float* __restrict__ wk,
    const float* __restrict__ wv, const float* __restrict__ wp,
    ushort_t* __restrict__ wbf)
{
  int i = blockIdx.x*256 + threadIdx.x;      // 0..262143
  int mat = i >> 16;
  int off = i & 65535;
  const float* src = (mat==0) ? wq : (mat==1) ? wk : (mat==2) ? wv : wp;
  wbf[i] = f2bf(src[off]);
}

// ---------------------------------------------------------------- kernel 2
// x (B,C,H,W) fp32 -> xT (B, HW, C) bf16  (transpose + convert)
__global__ __launch_bounds__(256) void xpose_kernel(
    const float* __restrict__ x, ushort_t* __restrict__ xT)
{
  __shared__ unsigned int tile[32][33];   // [c][pixel-pair], +1 pad breaks conflicts
  int p0 = blockIdx.x * 64;
  int c0 = blockIdx.y * 32;
  int b  = blockIdx.z;
  int tid = threadIdx.x;
  int tx = tid & 31, ty = tid >> 5;       // tx: pixel-pair, ty: c row group
  const float* xb = x + ((size_t)(b*CH + c0))*HWP;
  #pragma unroll
  for (int r = 0; r < 4; r++){
    int c = r*8 + ty;
    float2 v = *(const float2*)(xb + (size_t)c*HWP + p0 + tx*2);
    tile[c][tx] = (unsigned int)f2bf(v.x) | ((unsigned int)f2bf(v.y) << 16);
  }
  __syncthreads();
  int pv = tid >> 2, cq = tid & 3;        // pixel 0..63, c-octet 0..3
  ushort_t tmp[8];
  #pragma unroll
  for (int s = 0; s < 8; s++){
    unsigned int w = tile[cq*8 + s][pv >> 1];
    tmp[s] = (ushort_t)((pv & 1) ? (w >> 16) : (w & 0xffffu));
  }
  *(us8*)(xT + ((size_t)(b*HWP + p0 + pv))*CH + c0 + cq*8) = *(us8*)tmp;
}

// ---------------------------------------------------------------- kernel 3
// QKV GEMM: out[p][o] = sum_c xT[p][c] * w[o][c]; write q/k/v [b][head][p][hd] bf16
// m97 structure: 128x128 tile, BK=32, global_load_lds(16B), 4 waves x (4x4) MFMA 16x16x32
__global__ __launch_bounds__(256) void qkv_gemm(
    const ushort_t* __restrict__ xT, const ushort_t* __restrict__ wbf,
    ushort_t* __restrict__ qb, ushort_t* __restrict__ kb, ushort_t* __restrict__ vb)
{
  __shared__ ushort_t As[128*32];   // [m][k], 64B rows
  __shared__ ushort_t Bs[128*32];   // [n][k]
  int m0 = blockIdx.x * 128;
  int n0 = blockIdx.y * 128;
  int b  = blockIdx.z / 3;
  int mat= blockIdx.z % 3;
  int tid = threadIdx.x;
  int wave = tid >> 6, lane = tid & 63;
  const ushort_t* Abase = xT + ((size_t)(b*HWP + m0))*CH;
  const ushort_t* Bbase = wbf + mat*65536 + n0*CH;

  f4v acc[4][4];
  #pragma unroll
  for (int i=0;i<4;i++)
    #pragma unroll
    for (int j=0;j<4;j++) acc[i][j] = (f4v){0.f,0.f,0.f,0.f};

  int wm = wave & 1, wn = wave >> 1;
  int lane16 = lane & 15, quad = lane >> 4;
  int lrow = lane >> 2, lchunk = lane & 3;

  for (int kt = 0; kt < 8; kt++){
    #pragma unroll
    for (int inst = 0; inst < 2; inst++){
      int row0 = wave*32 + inst*16;
      gload_lds16(Abase + (size_t)(row0 + lrow)*CH + kt*32 + lchunk*8, &As[row0*32]);
      gload_lds16(Bbase + (size_t)(row0 + lrow)*CH + kt*32 + lchunk*8, &Bs[row0*32]);
    }
    __syncthreads();   // drains vmcnt -> staged data visible
    s8v a[4], bf[4];
    #pragma unroll
    for (int mi=0;mi<4;mi++) a[mi]  = *(const s8v*)&As[(wm*64 + mi*16 + lane16)*32 + quad*8];
    #pragma unroll
    for (int ni=0;ni<4;ni++) bf[ni] = *(const s8v*)&Bs[(wn*64 + ni*16 + lane16)*32 + quad*8];
    #pragma unroll
    for (int mi=0;mi<4;mi++)
      #pragma unroll
      for (int ni=0;ni<4;ni++)
        acc[mi][ni] = __builtin_amdgcn_mfma_f32_16x16x32_bf16(a[mi], bf[ni], acc[mi][ni], 0, 0, 0);
    __syncthreads();   // LDS consumed before next stage
  }

  ushort_t* dst = (mat==0) ? qb : (mat==1) ? kb : vb;
  float sc = (mat==0) ? SCALE : 1.0f;
  size_t obase = (size_t)b * NHEADS * HWP * HD;
  #pragma unroll
  for (int mi=0;mi<4;mi++){
    #pragma unroll
    for (int ni=0;ni<4;ni++){
      int o = n0 + wn*64 + ni*16 + lane16;     // C/D col = lane&15
      int head = o >> 5, hd = o & 31;
      #pragma unroll
      for (int r=0;r<4;r++){
        int m = m0 + wm*64 + mi*16 + quad*4 + r;   // C/D row = (lane>>4)*4 + reg
        dst[obase + ((size_t)head*HWP + m)*HD + hd] = f2bf(acc[mi][ni][r] * sc);
      }
    }
  }
}

// ---------------------------------------------------------------- kernel 4
// Neighborhood attention: block = 16x16 pixel tile for one (b, head).
// k/v halo (<=22x22, alloc 512 px) staged to LDS bf16; per-thread 49 fp32 logits,
// softmax, AV accumulate; write merged [b][pix][head*32+hd] bf16.
__global__ __launch_bounds__(256) void attn_kernel(
    const ushort_t* __restrict__ qb, const ushort_t* __restrict__ kb,
    const ushort_t* __restrict__ vb, const float* __restrict__ rpb,
    ushort_t* __restrict__ merged)
{
  __shared__ ushort_t kT[512*32];   // 32 KB  [halo pixel][hd]
  __shared__ ushort_t vT[512*32];   // 32 KB
  __shared__ float rps[169];        // rpb[head] 13x13
  int t = blockIdx.x;               // 0..35
  int i0 = (t/6)*16, j0 = (t%6)*16;
  int head = blockIdx.y, b = blockIdx.z;
  int tid = threadIdx.x;
  int wave = tid >> 6, lane = tid & 63;

  int hs0 = max(i0-3, 0);           // halo origin; needed rows always in [hs0, hs0+21]
  int ws0 = max(j0-3, 0);
  size_t kvbase = ((size_t)(b*NHEADS + head)) * HWP * HD;

  // halo stage: 512 px * 64 B = 32 KB per array = 32 wave-instrs (8 per wave)
  #pragma unroll
  for (int it = 0; it < 8; it++){
    int blk   = wave*8 + it;                 // 0..31, 1024 B each
    int idx16 = blk*64 + lane;               // 16B chunk index
    int hp = idx16 >> 2, chunk = idx16 & 3;
    int r  = hp / 22;                        // 0..23 (>=22 rows unused, clamped)
    int cc = hp - r*22;
    int gr = min(hs0 + r,  HH-1);
    int gc = min(ws0 + cc, WW-1);
    size_t gp = kvbase + ((size_t)(gr*WW + gc))*HD + chunk*8;
    gload_lds16(kb + gp, &kT[blk*512]);
    gload_lds16(vb + gp, &vT[blk*512]);
  }
  if (tid < 169) rps[tid] = rpb[head*169 + tid];

  int ti = tid >> 4, tj = tid & 15;
  int i = i0 + ti, j = j0 + tj;

  float qf[32];
  {
    const us8* qp = (const us8*)(qb + kvbase + ((size_t)(i*WW + j))*HD);
    #pragma unroll
    for (int g = 0; g < 4; g++){
      us8 v = qp[g];
      #pragma unroll
      for (int e = 0; e < 8; e++) qf[g*8+e] = bflo((unsigned int)v[e]);
    }
  }
  __syncthreads();   // halo staged (vmcnt drained) + rps visible

  int si_g = min(max(i-3,0), HH-KS);
  int sj_g = min(max(j-3,0), WW-KS);
  int si = si_g - hs0, sj = sj_g - ws0;      // local halo coords of window start
  int bi0 = si_g - i + 6, bj0 = sj_g - j + 6;

  float lg[49];
  #pragma unroll
  for (int ki = 0; ki < KS; ki++){
    #pragma unroll
    for (int kj = 0; kj < KS; kj++){
      const uint4* kv = (const uint4*)&kT[((si+ki)*22 + (sj+kj))*32];
      float d = 0.f;
      #pragma unroll
      for (int g = 0; g < 4; g++){
        uint4 kk = kv[g];
        d += qf[g*8+0]*bflo(kk.x) + qf[g*8+1]*bfhi(kk.x);
        d += qf[g*8+2]*bflo(kk.y) + qf[g*8+3]*bfhi(kk.y);
        d += qf[g*8+4]*bflo(kk.z) + qf[g*8+5]*bfhi(kk.z);
        d += qf[g*8+6]*bflo(kk.w) + qf[g*8+7]*bfhi(kk.w);
      }
      lg[ki*KS+kj] = d + rps[(bi0+ki)*13 + (bj0+kj)];
    }
  }

  float mx = lg[0];
  #pragma unroll
  for (int n = 1; n < 49; n++) mx = fmaxf(mx, lg[n]);
  float s = 0.f;
  #pragma unroll
  for (int n = 0; n < 49; n++){ float e = __expf(lg[n]-mx); lg[n] = e; s += e; }
  float inv = 1.0f / s;

  float acc[32];
  #pragma unroll
  for (int e = 0; e < 32; e++) acc[e] = 0.f;
  #pragma unroll
  for (int ki = 0; ki < KS; ki++){
    #pragma unroll
    for (int kj = 0; kj < KS; kj++){
      float w = lg[ki*KS+kj];
      const uint4* vv = (const uint4*)&vT[((si+ki)*22 + (sj+kj))*32];
      #pragma unroll
      for (int g = 0; g < 4; g++){
        uint4 u = vv[g];
        acc[g*8+0] += w*bflo(u.x); acc[g*8+1] += w*bfhi(u.x);
        acc[g*8+2] += w*bflo(u.y); acc[g*8+3] += w*bfhi(u.y);
        acc[g*8+4] += w*bflo(u.z); acc[g*8+5] += w*bfhi(u.z);
        acc[g*8+6] += w*bflo(u.w); acc[g*8+7] += w*bfhi(u.w);
      }
    }
  }

  ushort_t* mp = merged + ((size_t)(b*HWP + i*WW + j))*CH + head*HD;
  #pragma unroll
  for (int g = 0; g < 4; g++){
    us8 o;
    #pragma unroll
    for (int e = 0; e < 8; e++) o[e] = f2bf(acc[g*8+e]*inv);
    *(us8*)(mp + g*8) = o;
  }
}

// ---------------------------------------------------------------- kernel 5
// Output projection: y[b][o][p] = sum_c merged[b][p][c] * wp[o][c] + bias[o]
__global__ __launch_bounds__(256) void proj_gemm(
    const ushort_t* __restrict__ merged, const ushort_t* __restrict__ wbf,
    const float* __restrict__ bias, float* __restrict__ y)
{
  __shared__ ushort_t As[128*32];
  __shared__ ushort_t Bs[128*32];
  int m0 = blockIdx.x * 128;
  int n0 = blockIdx.y * 128;
  int b  = blockIdx.z;
  int tid = threadIdx.x;
  int wave = tid >> 6, lane = tid & 63;
  const ushort_t* Abase = merged + ((size_t)(b*HWP + m0))*CH;
  const ushort_t* Bbase = wbf + 3*65536 + n0*CH;

  f4v acc[4][4];
  #pragma unroll
  for (int i=0;i<4;i++)
    #pragma unroll
    for (int j=0;j<4;j++) acc[i][j] = (f4v){0.f,0.f,0.f,0.f};

  int wm = wave & 1, wn = wave >> 1;
  int lane16 = lane & 15, quad = lane >> 4;
  int lrow = lane >> 2, lchunk = lane & 3;

  for (int kt = 0; kt < 8; kt++){
    #pragma unroll
    for (int inst = 0; inst < 2; inst++){
      int row0 = wave*32 + inst*16;
      gload_lds16(Abase + (size_t)(row0 + lrow)*CH + kt*32 + lchunk*8, &As[row0*32]);
      gload_lds16(Bbase + (size_t)(row0 + lrow)*CH + kt*32 + lchunk*8, &Bs[row0*32]);
    }
    __syncthreads();
    s8v a[4], bf[4];
    #pragma unroll
    for (int mi=0;mi<4;mi++) a[mi]  = *(const s8v*)&As[(wm*64 + mi*16 + lane16)*32 + quad*8];
    #pragma unroll
    for (int ni=0;ni<4;ni++) bf[ni] = *(const s8v*)&Bs[(wn*64 + ni*16 + lane16)*32 + quad*8];
    #pragma unroll
    for (int mi=0;mi<4;mi++)
      #pragma unroll
      for (int ni=0;ni<4;ni++)
        acc[mi][ni] = __builtin_amdgcn_mfma_f32_16x16x32_bf16(a[mi], bf[ni], acc[mi][ni], 0, 0, 0);
    __syncthreads();
  }

  #pragma unroll
  for (int mi=0;mi<4;mi++){
    #pragma unroll
    for (int ni=0;ni<4;ni++){
      int o = n0 + wn*64 + ni*16 + lane16;
      float bo = bias[o];
      int mb = m0 + wm*64 + mi*16 + quad*4;
      float4 val;
      val.x = acc[mi][ni][0] + bo;
      val.y = acc[mi][ni][1] + bo;
      val.z = acc[mi][ni][2] + bo;
      val.w = acc[mi][ni][3] + bo;
      *(float4*)&y[((size_t)(b*CH + o))*HWP + mb] = val;
    }
  }
}

// ---------------------------------------------------------------- launch
extern "C" void kernel_launch(void* const* d_in, const int* in_sizes, int n_in,
                              void* d_out, int out_size, void* d_ws, size_t ws_size,
                              hipStream_t stream)
{
  const float* x   = (const float*)d_in[0];
  const float* wq  = (const float*)d_in[1];
  const float* wk  = (const float*)d_in[2];
  const float* wv  = (const float*)d_in[3];
  const float* wp  = (const float*)d_in[4];
  const float* bp  = (const float*)d_in[5];
  const float* rpb = (const float*)d_in[6];
  float* y = (float*)d_out;

  const size_t SZ = (size_t)BATCH * HWP * CH * 2;   // 37,748,736 B per bf16 tensor
  char* ws = (char*)d_ws;
  ushort_t* xT     = (ushort_t*)ws;  ws += SZ;
  ushort_t* qb     = (ushort_t*)ws;  ws += SZ;
  ushort_t* kbuf   = (ushort_t*)ws;  ws += SZ;
  ushort_t* vbuf   = (ushort_t*)ws;  ws += SZ;
  ushort_t* merged = (ushort_t*)ws;  ws += SZ;
  ushort_t* wbf    = (ushort_t*)ws;  ws += (size_t)4*65536*2;
  if (ws_size < (size_t)5*SZ + 4*65536*2) return;   // workspace too small — fail visibly

  wcvt_kernel <<<dim3(1024),        dim3(256), 0, stream>>>(wq, wk, wv, wp, wbf);
  xpose_kernel<<<dim3(144, 8, 8),   dim3(256), 0, stream>>>(x, xT);
  qkv_gemm    <<<dim3(72, 2, 24),   dim3(256), 0, stream>>>(xT, wbf, qb, kbuf, vbuf);
  attn_kernel <<<dim3(36, 8, 8),    dim3(256), 0, stream>>>(qb, kbuf, vbuf, rpb, merged);
  proj_gemm   <<<dim3(72, 2, 8),    dim3(256), 0, stream>>>(merged, wbf, bp, y);
}

// Round 2
// 361.503 us; speedup vs baseline: 1.9764x; 1.9764x over previous
//
#include <hip/hip_runtime.h>
#include <stdint.h>

// Problem constants
#define BATCH  8
#define CH     256
#define HH     96
#define WW     96
#define NHEADS 8
#define HD     32
#define KS     7
#define HWP    (HH*WW)          // 9216 pixels per image
#define SCALE  0.17677669529663687f   // 1/sqrt(32)

typedef unsigned short ushort_t;
typedef unsigned short us8 __attribute__((ext_vector_type(8)));
typedef short s8v __attribute__((ext_vector_type(8)));   // 8 bf16 in shorts (4 VGPRs) — MFMA A/B frag
typedef float f4v __attribute__((ext_vector_type(4)));   // MFMA C/D frag

// fp32 -> bf16 RNE
__device__ __forceinline__ ushort_t f2bf(float f){
  unsigned int u = __float_as_uint(f);
  u = u + 0x7fffu + ((u >> 16) & 1u);
  return (ushort_t)(u >> 16);
}
// unpack low/high bf16 of a uint to fp32
__device__ __forceinline__ float bflo(unsigned int u){ return __uint_as_float(u << 16); }
__device__ __forceinline__ float bfhi(unsigned int u){ return __uint_as_float(u & 0xffff0000u); }

// async global->LDS, 16B per lane; LDS dest = wave-uniform base + lane*16
__device__ __forceinline__ void gload_lds16(const void* g, void* l){
  __builtin_amdgcn_global_load_lds(
      (const __attribute__((address_space(1))) void*)g,
      (__attribute__((address_space(3))) void*)l, 16, 0, 0);
}

// ---------------------------------------------------------------- kernel 1
__global__ __launch_bounds__(256) void wcvt_kernel(
    const float* __restrict__ wq, const float* __restrict__ wk,
    const float* __restrict__ wv, const float* __restrict__ wp,
    ushort_t* __restrict__ wbf)
{
  int i = blockIdx.x*256 + threadIdx.x;
  int mat = i >> 16;
  int off = i & 65535;
  const float* src = (mat==0) ? wq : (mat==1) ? wk : (mat==2) ? wv : wp;
  wbf[i] = f2bf(src[off]);
}

// ---------------------------------------------------------------- kernel 2
// x (B,C,H,W) fp32 -> xT (B, HW, C) bf16  (transpose + convert)
__global__ __launch_bounds__(256) void xpose_kernel(
    const float* __restrict__ x, ushort_t* __restrict__ xT)
{
  __shared__ unsigned int tile[32][33];
  int p0 = blockIdx.x * 64;
  int c0 = blockIdx.y * 32;
  int b  = blockIdx.z;
  int tid = threadIdx.x;
  int tx = tid & 31, ty = tid >> 5;
  const float* xb = x + ((size_t)(b*CH + c0))*HWP;
  #pragma unroll
  for (int r = 0; r < 4; r++){
    int c = r*8 + ty;
    float2 v = *(const float2*)(xb + (size_t)c*HWP + p0 + tx*2);
    tile[c][tx] = (unsigned int)f2bf(v.x) | ((unsigned int)f2bf(v.y) << 16);
  }
  __syncthreads();
  int pv = tid >> 2, cq = tid & 3;
  ushort_t tmp[8];
  #pragma unroll
  for (int s = 0; s < 8; s++){
    unsigned int w = tile[cq*8 + s][pv >> 1];
    tmp[s] = (ushort_t)((pv & 1) ? (w >> 16) : (w & 0xffffu));
  }
  *(us8*)(xT + ((size_t)(b*HWP + p0 + pv))*CH + c0 + cq*8) = *(us8*)tmp;
}

// ---------------------------------------------------------------- kernel 3
// QKV GEMM: m97 structure, writes q(prescaled)/k/v as [b][head][pix][hd] bf16
__global__ __launch_bounds__(256) void qkv_gemm(
    const ushort_t* __restrict__ xT, const ushort_t* __restrict__ wbf,
    ushort_t* __restrict__ qb, ushort_t* __restrict__ kb, ushort_t* __restrict__ vb)
{
  __shared__ ushort_t As[128*32];
  __shared__ ushort_t Bs[128*32];
  int m0 = blockIdx.x * 128;
  int n0 = blockIdx.y * 128;
  int b  = blockIdx.z / 3;
  int mat= blockIdx.z % 3;
  int tid = threadIdx.x;
  int wave = tid >> 6, lane = tid & 63;
  const ushort_t* Abase = xT + ((size_t)(b*HWP + m0))*CH;
  const ushort_t* Bbase = wbf + mat*65536 + n0*CH;

  f4v acc[4][4];
  #pragma unroll
  for (int i=0;i<4;i++)
    #pragma unroll
    for (int j=0;j<4;j++) acc[i][j] = (f4v){0.f,0.f,0.f,0.f};

  int wm = wave & 1, wn = wave >> 1;
  int lane16 = lane & 15, quad = lane >> 4;
  int lrow = lane >> 2, lchunk = lane & 3;

  for (int kt = 0; kt < 8; kt++){
    #pragma unroll
    for (int inst = 0; inst < 2; inst++){
      int row0 = wave*32 + inst*16;
      gload_lds16(Abase + (size_t)(row0 + lrow)*CH + kt*32 + lchunk*8, &As[row0*32]);
      gload_lds16(Bbase + (size_t)(row0 + lrow)*CH + kt*32 + lchunk*8, &Bs[row0*32]);
    }
    __syncthreads();
    s8v a[4], bf[4];
    #pragma unroll
    for (int mi=0;mi<4;mi++) a[mi]  = *(const s8v*)&As[(wm*64 + mi*16 + lane16)*32 + quad*8];
    #pragma unroll
    for (int ni=0;ni<4;ni++) bf[ni] = *(const s8v*)&Bs[(wn*64 + ni*16 + lane16)*32 + quad*8];
    #pragma unroll
    for (int mi=0;mi<4;mi++)
      #pragma unroll
      for (int ni=0;ni<4;ni++)
        acc[mi][ni] = __builtin_amdgcn_mfma_f32_16x16x32_bf16(a[mi], bf[ni], acc[mi][ni], 0, 0, 0);
    __syncthreads();
  }

  ushort_t* dst = (mat==0) ? qb : (mat==1) ? kb : vb;
  float sc = (mat==0) ? SCALE : 1.0f;
  size_t obase = (size_t)b * NHEADS * HWP * HD;
  #pragma unroll
  for (int mi=0;mi<4;mi++){
    #pragma unroll
    for (int ni=0;ni<4;ni++){
      int o = n0 + wn*64 + ni*16 + lane16;
      int head = o >> 5, hd = o & 31;
      #pragma unroll
      for (int r=0;r<4;r++){
        int m = m0 + wm*64 + mi*16 + quad*4 + r;
        dst[obase + ((size_t)head*HWP + m)*HD + hd] = f2bf(acc[mi][ni][r] * sc);
      }
    }
  }
}

// ---------------------------------------------------------------- kernel 4
// Neighborhood attention, flash-style row-online softmax.
// Block = 16x16 query tile for one (b, head). k/v halo (22x22 -> 512 slots)
// staged to LDS in CHUNK-MAJOR layout: kT[c][pixel][16B] so compute-phase
// lane stride is 16 B (4 dwords) -> 2-way bank aliasing only (free).
// Per-thread state: qf[32], acc[32], row[7], m, l  (~100 VGPRs, no spill).
__global__ __launch_bounds__(256) void attn_kernel(
    const ushort_t* __restrict__ qb, const ushort_t* __restrict__ kb,
    const ushort_t* __restrict__ vb, const float* __restrict__ rpb,
    ushort_t* __restrict__ merged)
{
  __shared__ ushort_t kT[4*512*8];   // 32 KB, chunk-major: [c][pix][8 ushort]
  __shared__ ushort_t vT[4*512*8];   // 32 KB
  __shared__ float rps[169];
  int t = blockIdx.x;               // 0..35
  int i0 = (t/6)*16, j0 = (t%6)*16;
  int head = blockIdx.y, b = blockIdx.z;
  int tid = threadIdx.x;
  int wave = tid >> 6, lane = tid & 63;

  int hs0 = max(i0-3, 0);
  int ws0 = max(j0-3, 0);
  size_t kvbase = ((size_t)(b*NHEADS + head)) * HWP * HD;

  // stage halo: 8 pixel-blocks of 64; each block issues 4 k + 4 v chunk loads
  #pragma unroll
  for (int it = 0; it < 2; it++){
    int blk = wave*2 + it;                 // 0..7
    int p = blk*64 + lane;                 // halo pixel 0..511
    int r = p / 22;                        // 0..23
    int cc = p - r*22;
    int gr = min(hs0 + r,  HH-1);
    int gc = min(ws0 + cc, WW-1);
    size_t gp = kvbase + ((size_t)(gr*WW + gc))*HD;
    #pragma unroll
    for (int c = 0; c < 4; c++){
      gload_lds16(kb + gp + c*8, &kT[c*4096 + blk*512]);
      gload_lds16(vb + gp + c*8, &vT[c*4096 + blk*512]);
    }
  }
  if (tid < 169) rps[tid] = rpb[head*169 + tid];

  int ti = tid >> 4, tj = tid & 15;
  int i = i0 + ti, j = j0 + tj;

  float qf[32];
  {
    const us8* qp = (const us8*)(qb + kvbase + ((size_t)(i*WW + j))*HD);
    #pragma unroll
    for (int g = 0; g < 4; g++){
      us8 v = qp[g];
      #pragma unroll
      for (int e = 0; e < 8; e++) qf[g*8+e] = bflo((unsigned int)v[e]);
    }
  }
  __syncthreads();   // halo staged (vmcnt drained) + rps visible

  int si_g = min(max(i-3,0), HH-KS);
  int sj_g = min(max(j-3,0), WW-KS);
  int si = si_g - hs0, sj = sj_g - ws0;
  int bi0 = si_g - i + 6, bj0 = sj_g - j + 6;

  float m = -1e30f, l = 0.f;
  float acc[32];
  #pragma unroll
  for (int e = 0; e < 32; e++) acc[e] = 0.f;

  #pragma unroll 1
  for (int ki = 0; ki < KS; ki++){
    int hrow = (si + ki)*22 + sj;
    float row[KS];
    #pragma unroll
    for (int kj = 0; kj < KS; kj++){
      int hp = hrow + kj;
      float d = 0.f;
      #pragma unroll
      for (int c = 0; c < 4; c++){
        uint4 kk = *(const uint4*)&kT[c*4096 + hp*8];
        d += qf[c*8+0]*bflo(kk.x) + qf[c*8+1]*bfhi(kk.x);
        d += qf[c*8+2]*bflo(kk.y) + qf[c*8+3]*bfhi(kk.y);
        d += qf[c*8+4]*bflo(kk.z) + qf[c*8+5]*bfhi(kk.z);
        d += qf[c*8+6]*bflo(kk.w) + qf[c*8+7]*bfhi(kk.w);
      }
      row[kj] = d + rps[(bi0+ki)*13 + (bj0+kj)];
    }
    float rmax = row[0];
    #pragma unroll
    for (int kj = 1; kj < KS; kj++) rmax = fmaxf(rmax, row[kj]);
    float mnew = fmaxf(m, rmax);
    float alpha = __expf(m - mnew);
    l *= alpha;
    #pragma unroll
    for (int e = 0; e < 32; e++) acc[e] *= alpha;
    #pragma unroll
    for (int kj = 0; kj < KS; kj++){
      float w = __expf(row[kj] - mnew);
      l += w;
      int hp = hrow + kj;
      #pragma unroll
      for (int c = 0; c < 4; c++){
        uint4 u = *(const uint4*)&vT[c*4096 + hp*8];
        acc[c*8+0] += w*bflo(u.x); acc[c*8+1] += w*bfhi(u.x);
        acc[c*8+2] += w*bflo(u.y); acc[c*8+3] += w*bfhi(u.y);
        acc[c*8+4] += w*bflo(u.z); acc[c*8+5] += w*bfhi(u.z);
        acc[c*8+6] += w*bflo(u.w); acc[c*8+7] += w*bfhi(u.w);
      }
    }
    m = mnew;
  }
  float inv = 1.0f / l;

  ushort_t* mp = merged + ((size_t)(b*HWP + i*WW + j))*CH + head*HD;
  #pragma unroll
  for (int g = 0; g < 4; g++){
    us8 o;
    #pragma unroll
    for (int e = 0; e < 8; e++) o[e] = f2bf(acc[g*8+e]*inv);
    *(us8*)(mp + g*8) = o;
  }
}

// ---------------------------------------------------------------- kernel 5
__global__ __launch_bounds__(256) void proj_gemm(
    const ushort_t* __restrict__ merged, const ushort_t* __restrict__ wbf,
    const float* __restrict__ bias, float* __restrict__ y)
{
  __shared__ ushort_t As[128*32];
  __shared__ ushort_t Bs[128*32];
  int m0 = blockIdx.x * 128;
  int n0 = blockIdx.y * 128;
  int b  = blockIdx.z;
  int tid = threadIdx.x;
  int wave = tid >> 6, lane = tid & 63;
  const ushort_t* Abase = merged + ((size_t)(b*HWP + m0))*CH;
  const ushort_t* Bbase = wbf + 3*65536 + n0*CH;

  f4v acc[4][4];
  #pragma unroll
  for (int i=0;i<4;i++)
    #pragma unroll
    for (int j=0;j<4;j++) acc[i][j] = (f4v){0.f,0.f,0.f,0.f};

  int wm = wave & 1, wn = wave >> 1;
  int lane16 = lane & 15, quad = lane >> 4;
  int lrow = lane >> 2, lchunk = lane & 3;

  for (int kt = 0; kt < 8; kt++){
    #pragma unroll
    for (int inst = 0; inst < 2; inst++){
      int row0 = wave*32 + inst*16;
      gload_lds16(Abase + (size_t)(row0 + lrow)*CH + kt*32 + lchunk*8, &As[row0*32]);
      gload_lds16(Bbase + (size_t)(row0 + lrow)*CH + kt*32 + lchunk*8, &Bs[row0*32]);
    }
    __syncthreads();
    s8v a[4], bf[4];
    #pragma unroll
    for (int mi=0;mi<4;mi++) a[mi]  = *(const s8v*)&As[(wm*64 + mi*16 + lane16)*32 + quad*8];
    #pragma unroll
    for (int ni=0;ni<4;ni++) bf[ni] = *(const s8v*)&Bs[(wn*64 + ni*16 + lane16)*32 + quad*8];
    #pragma unroll
    for (int mi=0;mi<4;mi++)
      #pragma unroll
      for (int ni=0;ni<4;ni++)
        acc[mi][ni] = __builtin_amdgcn_mfma_f32_16x16x32_bf16(a[mi], bf[ni], acc[mi][ni], 0, 0, 0);
    __syncthreads();
  }

  #pragma unroll
  for (int mi=0;mi<4;mi++){
    #pragma unroll
    for (int ni=0;ni<4;ni++){
      int o = n0 + wn*64 + ni*16 + lane16;
      float bo = bias[o];
      int mb = m0 + wm*64 + mi*16 + quad*4;
      float4 val;
      val.x = acc[mi][ni][0] + bo;
      val.y = acc[mi][ni][1] + bo;
      val.z = acc[mi][ni][2] + bo;
      val.w = acc[mi][ni][3] + bo;
      *(float4*)&y[((size_t)(b*CH + o))*HWP + mb] = val;
    }
  }
}

// ---------------------------------------------------------------- launch
extern "C" void kernel_launch(void* const* d_in, const int* in_sizes, int n_in,
                              void* d_out, int out_size, void* d_ws, size_t ws_size,
                              hipStream_t stream)
{
  const float* x   = (const float*)d_in[0];
  const float* wq  = (const float*)d_in[1];
  const float* wk  = (const float*)d_in[2];
  const float* wv  = (const float*)d_in[3];
  const float* wp  = (const float*)d_in[4];
  const float* bp  = (const float*)d_in[5];
  const float* rpb = (const float*)d_in[6];
  float* y = (float*)d_out;

  const size_t SZ = (size_t)BATCH * HWP * CH * 2;
  char* ws = (char*)d_ws;
  ushort_t* xT     = (ushort_t*)ws;  ws += SZ;
  ushort_t* qb     = (ushort_t*)ws;  ws += SZ;
  ushort_t* kbuf   = (ushort_t*)ws;  ws += SZ;
  ushort_t* vbuf   = (ushort_t*)ws;  ws += SZ;
  ushort_t* merged = (ushort_t*)ws;  ws += SZ;
  ushort_t* wbf    = (ushort_t*)ws;  ws += (size_t)4*65536*2;
  if (ws_size < (size_t)5*SZ + 4*65536*2) return;

  wcvt_kernel <<<dim3(1024),        dim3(256), 0, stream>>>(wq, wk, wv, wp, wbf);
  xpose_kernel<<<dim3(144, 8, 8),   dim3(256), 0, stream>>>(x, xT);
  qkv_gemm    <<<dim3(72, 2, 24),   dim3(256), 0, stream>>>(xT, wbf, qb, kbuf, vbuf);
  attn_kernel <<<dim3(36, 8, 8),    dim3(256), 0, stream>>>(qb, kbuf, vbuf, rpb, merged);
  proj_gemm   <<<dim3(72, 2, 8),    dim3(256), 0, stream>>>(merged, wbf, bp, y);
}